// Round 1
// baseline (777.838 us; speedup 1.0000x reference)
//
#include <hip/hip_runtime.h>
#include <math.h>

#define HIDDEN 4096
#define INTER  11008
#define NTOK   128

typedef _Float16 half8 __attribute__((ext_vector_type(8)));
typedef float    f32x4 __attribute__((ext_vector_type(4)));

__device__ __forceinline__ f32x4 mfma16(half8 a, half8 b, f32x4 c) {
  return __builtin_amdgcn_mfma_f32_16x16x32_f16(a, b, c, 0, 0, 0);
}

__device__ __forceinline__ _Float16 dq1(int v, float s, float m) {
  return (_Float16)((float)v * s + m);
}

// ---------------- Kernel 1: RMSNorm -> x fp16 ----------------
__global__ __launch_bounds__(256) void k_rmsnorm(const float* __restrict__ in,
                                                 const float* __restrict__ nw,
                                                 _Float16* __restrict__ xo) {
  const int tok = blockIdx.x;
  const int tid = threadIdx.x;
  const float* row = in + (size_t)tok * HIDDEN;
  float4 v[4];
  float ss = 0.f;
#pragma unroll
  for (int j = 0; j < 4; ++j) {
    v[j] = *(const float4*)&row[tid * 4 + j * 1024];
    ss += v[j].x * v[j].x + v[j].y * v[j].y + v[j].z * v[j].z + v[j].w * v[j].w;
  }
#pragma unroll
  for (int o = 32; o; o >>= 1) ss += __shfl_xor(ss, o);
  __shared__ float wsum[4];
  if ((tid & 63) == 0) wsum[tid >> 6] = ss;
  __syncthreads();
  ss = wsum[0] + wsum[1] + wsum[2] + wsum[3];
  const float rs = rsqrtf(ss * (1.f / HIDDEN) + 1e-6f);
#pragma unroll
  for (int j = 0; j < 4; ++j) {
    const int k = tid * 4 + j * 1024;
    const float4 w = *(const float4*)&nw[k];
    union { _Float16 h[4]; uint2 u; } p;
    p.h[0] = (_Float16)(v[j].x * rs * w.x);
    p.h[1] = (_Float16)(v[j].y * rs * w.y);
    p.h[2] = (_Float16)(v[j].z * rs * w.z);
    p.h[3] = (_Float16)(v[j].w * rs * w.w);
    *(uint2*)&xo[(size_t)tok * HIDDEN + k] = p.u;
  }
}

// ---------------- Kernel 2: gate/up GEMM + SiLU -> h fp16 ----------------
// Grid: 344 blocks (inter tiles of 32). Block: 256 thr = 4 waves.
// wave = (coltile = w&1) x (khalf = w>>1). Each wave: 16 inter cols, K half (2048).
__global__ __launch_bounds__(256) void k_gateup(const _Float16* __restrict__ x,
                                                const int* __restrict__ q,
                                                const float* __restrict__ sm,
                                                _Float16* __restrict__ h) {
  const int tid   = threadIdx.x;
  const int lane  = tid & 63;
  const int wave  = tid >> 6;
  const int colt  = wave & 1;
  const int khalf = wave >> 1;
  const int colbase = blockIdx.x * 32 + colt * 16;
  const int l15  = lane & 15;
  const int bcol = colbase + l15;        // inter row this lane loads weights for
  const int koff = (lane >> 4) * 8;      // k sub-offset of the B fragment

  f32x4 aG[8], aU[8];
  const f32x4 zz = {0.f, 0.f, 0.f, 0.f};
#pragma unroll
  for (int m = 0; m < 8; ++m) { aG[m] = zz; aU[m] = zz; }

  const int*   qrow  = q  + (size_t)bcol * (HIDDEN * 2);
  const float* smrow = sm + (size_t)bcol * 128;   // [2][32][2] floats per row

  for (int grp = khalf * 16; grp < khalf * 16 + 16; ++grp) {
    const float2 sg = *(const float2*)&smrow[grp * 2];       // gate {scale,min}
    const float2 su = *(const float2*)&smrow[64 + grp * 2];  // up   {scale,min}
#pragma unroll 2
    for (int t = 0; t < 4; ++t) {
      const int kb = grp * 128 + t * 32 + koff;
      const int4 b0 = *(const int4*)&qrow[(size_t)kb * 2 + 0];
      const int4 b1 = *(const int4*)&qrow[(size_t)kb * 2 + 4];
      const int4 b2 = *(const int4*)&qrow[(size_t)kb * 2 + 8];
      const int4 b3 = *(const int4*)&qrow[(size_t)kb * 2 + 12];
      half8 bg, bu;
      bg[0] = dq1(b0.x, sg.x, sg.y); bu[0] = dq1(b0.y, su.x, su.y);
      bg[1] = dq1(b0.z, sg.x, sg.y); bu[1] = dq1(b0.w, su.x, su.y);
      bg[2] = dq1(b1.x, sg.x, sg.y); bu[2] = dq1(b1.y, su.x, su.y);
      bg[3] = dq1(b1.z, sg.x, sg.y); bu[3] = dq1(b1.w, su.x, su.y);
      bg[4] = dq1(b2.x, sg.x, sg.y); bu[4] = dq1(b2.y, su.x, su.y);
      bg[5] = dq1(b2.z, sg.x, sg.y); bu[5] = dq1(b2.w, su.x, su.y);
      bg[6] = dq1(b3.x, sg.x, sg.y); bu[6] = dq1(b3.y, su.x, su.y);
      bg[7] = dq1(b3.z, sg.x, sg.y); bu[7] = dq1(b3.w, su.x, su.y);
      const _Float16* xp = x + kb;
#pragma unroll
      for (int m = 0; m < 8; ++m) {
        const half8 a = *(const half8*)&xp[(size_t)(m * 16 + l15) * HIDDEN];
        aG[m] = mfma16(a, bg, aG[m]);
        aU[m] = mfma16(a, bu, aU[m]);
      }
    }
  }

  // reduce the two K-halves: waves 2,3 -> LDS, waves 0,1 add + epilogue
  __shared__ float red[2][8][2][64][4];  // 32 KB
  if (khalf == 1) {
#pragma unroll
    for (int m = 0; m < 8; ++m) {
      *(f32x4*)&red[colt][m][0][lane][0] = aG[m];
      *(f32x4*)&red[colt][m][1][lane][0] = aU[m];
    }
  }
  __syncthreads();
  if (khalf == 0) {
    const int trow = (lane >> 4) * 4;
#pragma unroll
    for (int m = 0; m < 8; ++m) {
      const f32x4 g2 = *(const f32x4*)&red[colt][m][0][lane][0];
      const f32x4 u2 = *(const f32x4*)&red[colt][m][1][lane][0];
#pragma unroll
      for (int r = 0; r < 4; ++r) {
        const float g = aG[m][r] + g2[r];
        const float u = aU[m][r] + u2[r];
        const float hv = g / (1.f + __expf(-g)) * u;
        const int token = m * 16 + trow + r;
        h[(size_t)token * INTER + colbase + l15] = (_Float16)hv;
      }
    }
  }
}

// ---------------- Kernel 3: down GEMM -> f32 partials ----------------
// Grid: 512 = 128 hidden-tiles(32) x 4 K-splits. Block: 4 waves = 2 coltiles x 2 khalf.
__global__ __launch_bounds__(256) void k_down(const _Float16* __restrict__ h,
                                              const int* __restrict__ q,
                                              const float* __restrict__ sm,
                                              float* __restrict__ part) {
  const int tid   = threadIdx.x;
  const int lane  = tid & 63;
  const int wave  = tid >> 6;
  const int colt  = wave & 1;
  const int khalf = wave >> 1;
  const int ntile = blockIdx.x >> 2;
  const int kblk  = blockIdx.x & 3;
  const int colbase = ntile * 32 + colt * 16;
  const int l15  = lane & 15;
  const int bcol = colbase + l15;        // hidden row
  const int koff = (lane >> 4) * 8;
  const int KW   = INTER / 8;            // 1376 per wave
  const int kstart = (kblk * 2 + khalf) * KW;

  f32x4 acc[8];
  const f32x4 zz = {0.f, 0.f, 0.f, 0.f};
#pragma unroll
  for (int m = 0; m < 8; ++m) acc[m] = zz;

  const int*   qrow  = q  + (size_t)bcol * INTER;
  const float* smrow = sm + (size_t)bcol * (86 * 2);

#pragma unroll 2
  for (int kk = 0; kk < KW / 32; ++kk) {  // 43 iters
    const int k0 = kstart + kk * 32;
    const int kb = k0 + koff;
    const int grp = k0 >> 7;
    const float2 s = *(const float2*)&smrow[grp * 2];
    const int4 b0 = *(const int4*)&qrow[kb];
    const int4 b1 = *(const int4*)&qrow[kb + 4];
    half8 bw;
    bw[0] = dq1(b0.x, s.x, s.y);
    bw[1] = dq1(b0.y, s.x, s.y);
    bw[2] = dq1(b0.z, s.x, s.y);
    bw[3] = dq1(b0.w, s.x, s.y);
    bw[4] = dq1(b1.x, s.x, s.y);
    bw[5] = dq1(b1.y, s.x, s.y);
    bw[6] = dq1(b1.z, s.x, s.y);
    bw[7] = dq1(b1.w, s.x, s.y);
    const _Float16* hp = h + kb;
#pragma unroll
    for (int m = 0; m < 8; ++m) {
      const half8 a = *(const half8*)&hp[(size_t)(m * 16 + l15) * INTER];
      acc[m] = mfma16(a, bw, acc[m]);
    }
  }

  __shared__ float red[2][8][64][4];  // 16 KB
  if (khalf == 1) {
#pragma unroll
    for (int m = 0; m < 8; ++m) *(f32x4*)&red[colt][m][lane][0] = acc[m];
  }
  __syncthreads();
  if (khalf == 0) {
    float* pb = part + (size_t)kblk * ((size_t)NTOK * HIDDEN);
    const int trow = (lane >> 4) * 4;
#pragma unroll
    for (int m = 0; m < 8; ++m) {
      const f32x4 o = *(const f32x4*)&red[colt][m][lane][0];
#pragma unroll
      for (int r = 0; r < 4; ++r) {
        const int token = m * 16 + trow + r;
        pb[(size_t)token * HIDDEN + colbase + l15] = acc[m][r] + o[r];
      }
    }
  }
}

// ---------------- Kernel 4: sum partials + residual ----------------
__global__ __launch_bounds__(256) void k_final(const float* __restrict__ res,
                                               const float* __restrict__ part,
                                               float* __restrict__ out) {
  const int i = blockIdx.x * 256 + threadIdx.x;
#pragma unroll
  for (int j = 0; j < 2; ++j) {
    const size_t idx = ((size_t)j * 65536 + i) * 4;
    float4 a        = *(const float4*)&res[idx];
    const float4 p0 = *(const float4*)&part[idx];
    const float4 p1 = *(const float4*)&part[(size_t)1 * NTOK * HIDDEN + idx];
    const float4 p2 = *(const float4*)&part[(size_t)2 * NTOK * HIDDEN + idx];
    const float4 p3 = *(const float4*)&part[(size_t)3 * NTOK * HIDDEN + idx];
    a.x += p0.x + p1.x + p2.x + p3.x;
    a.y += p0.y + p1.y + p2.y + p3.y;
    a.z += p0.z + p1.z + p2.z + p3.z;
    a.w += p0.w + p1.w + p2.w + p3.w;
    *(float4*)&out[idx] = a;
  }
}

extern "C" void kernel_launch(void* const* d_in, const int* in_sizes, int n_in,
                              void* d_out, int out_size, void* d_ws, size_t ws_size,
                              hipStream_t stream) {
  const float* inp  = (const float*)d_in[0];
  const float* res  = (const float*)d_in[1];
  const float* nw   = (const float*)d_in[2];
  const int*   guq  = (const int*)d_in[3];
  const float* gusm = (const float*)d_in[4];
  const int*   dq   = (const int*)d_in[5];
  const float* dsm  = (const float*)d_in[6];
  float* out = (float*)d_out;

  char* ws = (char*)d_ws;
  _Float16* x    = (_Float16*)ws;                     // 128*4096*2   = 1 MB
  _Float16* hbuf = (_Float16*)(ws + (1u << 20));      // 128*11008*2  = 2.75 MB
  float*    part = (float*)(ws + (4u << 20));         // 4*128*4096*4 = 8 MB

  k_rmsnorm<<<NTOK, 256, 0, stream>>>(inp, nw, x);
  k_gateup<<<INTER / 32, 256, 0, stream>>>(x, guq, gusm, hbuf);
  k_down<<<(HIDDEN / 32) * 4, 256, 0, stream>>>(hbuf, dq, dsm, part);
  k_final<<<256, 256, 0, stream>>>(res, part, out);
}